// Round 1
// baseline (728.608 us; speedup 1.0000x reference)
//
#include <hip/hip_runtime.h>
#include <hip/hip_bf16.h>

#define N_NODES 20000
#define N_EDGES 180000
#define D_OUT   768
#define D_H1    128
#define B_SZ    16
#define S_LEN   512
#define NEG_SLOPE_C 0.2f

__device__ __forceinline__ float leaky1(float x){ return x >= 0.0f ? x : NEG_SLOPE_C * x; }

// ---------------- CSR build (by destination) ----------------
__global__ void k_count(const int* __restrict__ ed, int* __restrict__ deg){
  int e = blockIdx.x*256 + threadIdx.x;
  if(e < N_EDGES) atomicAdd(&deg[ed[e]], 1);
}

__global__ void k_scan(const int* __restrict__ deg, int* __restrict__ row_ptr, int* __restrict__ cursor){
  __shared__ int part[256];
  int t = threadIdx.x;
  const int CH = (N_NODES + 255) / 256; // 79 nodes per thread
  int base = t * CH;
  int s = 0;
  for(int i=0;i<CH;i++){ int n = base+i; if(n < N_NODES) s += deg[n]; }
  part[t] = s;
  __syncthreads();
  for(int off=1; off<256; off<<=1){
    int v = (t >= off) ? part[t-off] : 0;
    __syncthreads();
    part[t] += v;
    __syncthreads();
  }
  int run = (t==0) ? 0 : part[t-1];
  for(int i=0;i<CH;i++){
    int n = base+i;
    if(n < N_NODES){ row_ptr[n] = run; cursor[n] = run; run += deg[n]; }
  }
  if(t == 255) row_ptr[N_NODES] = run; // == N_EDGES
}

__global__ void k_scatter(const int* __restrict__ ed, int* __restrict__ cursor, int* __restrict__ eidx){
  int e = blockIdx.x*256 + threadIdx.x;
  if(e < N_EDGES){
    int pos = atomicAdd(&cursor[ed[e]], 1);
    eidx[pos] = e;
  }
}

// ---------------- Layer 1: node transforms (K=4) ----------------
__global__ void k_gemm1(const float* __restrict__ feat, const float* __restrict__ Ws,
                        const float* __restrict__ Wd, float* __restrict__ hs1, float* __restrict__ hd1){
  int idx = blockIdx.x*256 + threadIdx.x;
  if(idx >= N_NODES*D_H1) return;
  int n = idx >> 7, hf = idx & 127;
  float f0 = feat[n*4+0], f1 = feat[n*4+1], f2 = feat[n*4+2], f3 = feat[n*4+3];
  hs1[idx] = f0*Ws[hf] + f1*Ws[128+hf] + f2*Ws[256+hf] + f3*Ws[384+hf];
  hd1[idx] = f0*Wd[hf] + f1*Wd[128+hf] + f2*Wd[256+hf] + f3*Wd[384+hf];
}

// ---------------- Layer 1: edge scores (wave per edge, 8 heads x 16) ----------------
__global__ void k_score1(const float* __restrict__ hs1, const float* __restrict__ hd1,
                         const int* __restrict__ es, const int* __restrict__ ed,
                         const float* __restrict__ attn1, float* __restrict__ score1){
  int wid = blockIdx.x*4 + (threadIdx.x >> 6);
  int l = threadIdx.x & 63;
  if(wid >= N_EDGES) return;
  int s = es[wid], d = ed[wid];
  const float* ps = hs1 + (size_t)s*D_H1;
  const float* pd = hd1 + (size_t)d*D_H1;
  float v0 = leaky1(ps[l]      + pd[l])      * attn1[l];
  float v1 = leaky1(ps[64 + l] + pd[64 + l]) * attn1[64 + l];
  #pragma unroll
  for(int off=1; off<16; off<<=1){
    v0 += __shfl_xor(v0, off, 64);
    v1 += __shfl_xor(v1, off, 64);
  }
  if((l & 15) == 0){
    score1[wid*8 + (l>>4)]     = v0;  // heads 0..3
    score1[wid*8 + 4 + (l>>4)] = v1;  // heads 4..7
  }
}

// ---------------- Layer 1: pull aggregate + softmax + ELU (wave per node) ----------------
__global__ void k_agg1(const float* __restrict__ hs1, const float* __restrict__ score1,
                       const int* __restrict__ es, const int* __restrict__ row_ptr,
                       const int* __restrict__ eidx, float* __restrict__ h1){
  int node = blockIdx.x*4 + (threadIdx.x >> 6);
  int l = threadIdx.x & 63;
  if(node >= N_NODES) return;
  int rp = row_ptr[node], re = row_ptr[node+1];
  int h0  = l >> 4;      // head of element l
  int h1i = h0 + 4;      // head of element 64+l
  float m0 = -INFINITY, m1 = -INFINITY;
  for(int k=rp;k<re;k++){
    int e = eidx[k];
    m0 = fmaxf(m0, score1[e*8+h0]);
    m1 = fmaxf(m1, score1[e*8+h1i]);
  }
  float d0 = 0.f, d1 = 0.f;
  for(int k=rp;k<re;k++){
    int e = eidx[k];
    d0 += expf(score1[e*8+h0]  - m0);
    d1 += expf(score1[e*8+h1i] - m1);
  }
  float r0 = 1.0f/d0, r1 = 1.0f/d1;
  float a0 = 0.f, a1 = 0.f;
  for(int k=rp;k<re;k++){
    int e = eidx[k]; int s = es[e];
    float w0 = expf(score1[e*8+h0]  - m0) * r0;
    float w1 = expf(score1[e*8+h1i] - m1) * r1;
    a0 += w0 * hs1[(size_t)s*D_H1 + l];
    a1 += w1 * hs1[(size_t)s*D_H1 + 64 + l];
  }
  // fused ELU
  h1[(size_t)node*D_H1 + l]      = a0 > 0.f ? a0 : expm1f(a0);
  h1[(size_t)node*D_H1 + 64 + l] = a1 > 0.f ? a1 : expm1f(a1);
}

// ---------------- Layer 2: two fused GEMMs (20000x128)@(128x768) ----------------
__global__ __launch_bounds__(256) void k_gemm2(const float* __restrict__ h1, const float* __restrict__ Ws,
                        const float* __restrict__ Wd, float* __restrict__ hs2, float* __restrict__ hd2){
  __shared__ float lt[16][8];
  int m0  = blockIdx.x * 16;
  int c0  = blockIdx.y * 64;
  int col = threadIdx.x & 63;
  int rq  = threadIdx.x >> 6;    // 0..3
  float as[4] = {0,0,0,0}, ad[4] = {0,0,0,0};
  for(int k0=0; k0<D_H1; k0+=8){
    __syncthreads();
    if(threadIdx.x < 128){
      int r = threadIdx.x >> 3, kk = threadIdx.x & 7;
      lt[r][kk] = h1[(size_t)(m0+r)*D_H1 + k0 + kk];
    }
    __syncthreads();
    #pragma unroll
    for(int kk=0; kk<8; kk++){
      float ws = Ws[(size_t)(k0+kk)*D_OUT + c0 + col];
      float wd = Wd[(size_t)(k0+kk)*D_OUT + c0 + col];
      #pragma unroll
      for(int i=0;i<4;i++){
        float hv = lt[rq*4+i][kk];
        as[i] += hv*ws;
        ad[i] += hv*wd;
      }
    }
  }
  #pragma unroll
  for(int i=0;i<4;i++){
    int r = m0 + rq*4 + i;
    hs2[(size_t)r*D_OUT + c0 + col] = as[i];
    hd2[(size_t)r*D_OUT + c0 + col] = ad[i];
  }
}

// ---------------- Layer 2: edge scores (wave per edge, 768-dot) ----------------
__global__ void k_score2(const float* __restrict__ hs2, const float* __restrict__ hd2,
                         const int* __restrict__ es, const int* __restrict__ ed,
                         const float* __restrict__ attn2, float* __restrict__ score2){
  int wid = blockIdx.x*4 + (threadIdx.x >> 6);
  int l = threadIdx.x & 63;
  if(wid >= N_EDGES) return;
  int s = es[wid], d = ed[wid];
  const float4* ps = (const float4*)(hs2 + (size_t)s*D_OUT);
  const float4* pd = (const float4*)(hd2 + (size_t)d*D_OUT);
  const float4* pa = (const float4*)attn2;
  float acc = 0.f;
  #pragma unroll
  for(int j=0;j<3;j++){
    int idx = j*64 + l;
    float4 a = ps[idx], b = pd[idx], w = pa[idx];
    acc += leaky1(a.x+b.x)*w.x + leaky1(a.y+b.y)*w.y
         + leaky1(a.z+b.z)*w.z + leaky1(a.w+b.w)*w.w;
  }
  #pragma unroll
  for(int off=32; off>0; off>>=1) acc += __shfl_xor(acc, off, 64);
  if(l==0) score2[wid] = acc;
}

// ---------------- Layer 2: pull aggregate + softmax (block per node) ----------------
__global__ __launch_bounds__(192) void k_agg2(const float* __restrict__ hs2, const float* __restrict__ score2,
                       const int* __restrict__ es, const int* __restrict__ row_ptr,
                       const int* __restrict__ eidx, float* __restrict__ h2){
  int node = blockIdx.x;
  int t = threadIdx.x;               // float4 index 0..191
  int rp = row_ptr[node], re = row_ptr[node+1];
  float m = -INFINITY;
  for(int k=rp;k<re;k++) m = fmaxf(m, score2[eidx[k]]);
  float den = 0.f;
  for(int k=rp;k<re;k++) den += expf(score2[eidx[k]] - m);
  float rden = 1.0f/den;
  float4 acc = make_float4(0.f,0.f,0.f,0.f);
  for(int k=rp;k<re;k++){
    int e = eidx[k];
    float a = expf(score2[e] - m) * rden;
    float4 v = ((const float4*)(hs2 + (size_t)es[e]*D_OUT))[t];
    acc.x += a*v.x; acc.y += a*v.y; acc.z += a*v.z; acc.w += a*v.w;
  }
  ((float4*)(h2 + (size_t)node*D_OUT))[t] = acc;
}

// ---------------- Output assembly: gathers + positional embedding ----------------
__global__ __launch_bounds__(192) void k_out(const float* __restrict__ h2,
    const int* __restrict__ tok, const int* __restrict__ mins, const int* __restrict__ wkd,
    const int* __restrict__ dayl, const int* __restrict__ grd,
    const float* __restrict__ grid_t, const float* __restrict__ dayt_t,
    const float* __restrict__ week_t, const float* __restrict__ day_t,
    float* __restrict__ out){
  int bs = blockIdx.x;               // b*512 + s
  int t  = threadIdx.x;              // float4 index 0..191
  int s  = bs & (S_LEN-1);
  int tk = tok[bs], mn = mins[bs], wk = wkd[bs], dy = dayl[bs], gr = grd[bs];
  float4 r = ((const float4*)(h2 + (size_t)tk*D_OUT))[t];
  float4 v;
  v = ((const float4*)(week_t + (size_t)wk*D_OUT))[t]; r.x+=v.x; r.y+=v.y; r.z+=v.z; r.w+=v.w;
  v = ((const float4*)(dayt_t + (size_t)mn*D_OUT))[t]; r.x+=v.x; r.y+=v.y; r.z+=v.z; r.w+=v.w;
  v = ((const float4*)(day_t  + (size_t)dy*D_OUT))[t]; r.x+=v.x; r.y+=v.y; r.z+=v.z; r.w+=v.w;
  v = ((const float4*)(grid_t + (size_t)gr*D_OUT))[t]; r.x+=v.x; r.y+=v.y; r.z+=v.z; r.w+=v.w;
  // positional embedding: elements 4t..4t+3 -> pairs i=2t (sin,cos), i=2t+1 (sin,cos)
  const float K = 0.011992630692677313f;   // ln(10000)/768
  float d0 = expf(-K * (float)(4*t));
  float d1 = expf(-K * (float)(4*t+2));
  float sf = (float)s;
  r.x += sinf(sf*d0); r.y += cosf(sf*d0);
  r.z += sinf(sf*d1); r.w += cosf(sf*d1);
  ((float4*)(out + (size_t)bs*D_OUT))[t] = r;
}

extern "C" void kernel_launch(void* const* d_in, const int* in_sizes, int n_in,
                              void* d_out, int out_size, void* d_ws, size_t ws_size,
                              hipStream_t stream) {
  const int*   trj   = (const int*)  d_in[0];
  const int*   mins  = (const int*)  d_in[1];
  const int*   wkd   = (const int*)  d_in[2];
  const int*   dayl  = (const int*)  d_in[3];
  const int*   grd   = (const int*)  d_in[4];
  /* d_in[5] poi_list: unused by reference */
  const int*   es    = (const int*)  d_in[6];
  const int*   ed    = (const int*)  d_in[7];
  const float* feat  = (const float*)d_in[8];
  const float* Ws1   = (const float*)d_in[9];
  const float* Wd1   = (const float*)d_in[10];
  const float* attn1 = (const float*)d_in[11];
  const float* Ws2   = (const float*)d_in[12];
  const float* Wd2   = (const float*)d_in[13];
  const float* attn2 = (const float*)d_in[14];
  const float* gridt = (const float*)d_in[15];
  const float* daytt = (const float*)d_in[16];
  const float* weekt = (const float*)d_in[17];
  const float* dayt  = (const float*)d_in[18];
  float* out = (float*)d_out;

  char* ws = (char*)d_ws;
  size_t off = 0;
  auto alloc = [&](size_t bytes)->char*{
    char* p = ws + off;
    off += bytes;
    off = (off + 255) & ~(size_t)255;
    return p;
  };
  float* hs1    = (float*)alloc((size_t)N_NODES*D_H1*4);
  float* hd1    = (float*)alloc((size_t)N_NODES*D_H1*4);
  float* h1     = (float*)alloc((size_t)N_NODES*D_H1*4);
  float* score1 = (float*)alloc((size_t)N_EDGES*8*4);
  float* hs2    = (float*)alloc((size_t)N_NODES*D_OUT*4);
  float* hd2    = (float*)alloc((size_t)N_NODES*D_OUT*4);
  float* h2     = (float*)alloc((size_t)N_NODES*D_OUT*4);
  float* score2 = (float*)alloc((size_t)N_EDGES*4);
  int* deg      = (int*)alloc((size_t)N_NODES*4);
  int* row_ptr  = (int*)alloc((size_t)(N_NODES+1)*4);
  int* cursor   = (int*)alloc((size_t)N_NODES*4);
  int* eidx     = (int*)alloc((size_t)N_EDGES*4);

  // CSR by destination (ws is poisoned each run -> must zero deg)
  hipMemsetAsync(deg, 0, (size_t)N_NODES*4, stream);
  k_count  <<<(N_EDGES+255)/256, 256, 0, stream>>>(ed, deg);
  k_scan   <<<1, 256, 0, stream>>>(deg, row_ptr, cursor);
  k_scatter<<<(N_EDGES+255)/256, 256, 0, stream>>>(ed, cursor, eidx);

  // Layer 1
  k_gemm1 <<<(N_NODES*D_H1)/256, 256, 0, stream>>>(feat, Ws1, Wd1, hs1, hd1);
  k_score1<<<(N_EDGES+3)/4, 256, 0, stream>>>(hs1, hd1, es, ed, attn1, score1);
  k_agg1  <<<(N_NODES+3)/4, 256, 0, stream>>>(hs1, score1, es, row_ptr, eidx, h1);

  // Layer 2
  dim3 g2(N_NODES/16, D_OUT/64);
  k_gemm2 <<<g2, 256, 0, stream>>>(h1, Ws2, Wd2, hs2, hd2);
  k_score2<<<(N_EDGES+3)/4, 256, 0, stream>>>(hs2, hd2, es, ed, attn2, score2);
  k_agg2  <<<N_NODES, 192, 0, stream>>>(hs2, score2, es, row_ptr, eidx, h2);

  // Output
  k_out<<<B_SZ*S_LEN, 192, 0, stream>>>(h2, trj, mins, wkd, dayl, grd,
                                        gridt, daytt, weekt, dayt, out);
}

// Round 2
// 486.666 us; speedup vs baseline: 1.4971x; 1.4971x over previous
//
#include <hip/hip_runtime.h>
#include <hip/hip_bf16.h>

#define N_NODES 20000
#define N_EDGES 180000
#define D_OUT   768
#define D_H1    128
#define B_SZ    16
#define S_LEN   512
#define NEG_SLOPE_C 0.2f

__device__ __forceinline__ float leaky1(float x){ return x >= 0.0f ? x : NEG_SLOPE_C * x; }

// ---------------- CSR build (by destination) ----------------
__global__ void k_count(const int* __restrict__ ed, int* __restrict__ deg){
  int e = blockIdx.x*256 + threadIdx.x;
  if(e < N_EDGES) atomicAdd(&deg[ed[e]], 1);
}

__global__ void k_scan(const int* __restrict__ deg, int* __restrict__ row_ptr, int* __restrict__ cursor){
  __shared__ int part[256];
  int t = threadIdx.x;
  const int CH = (N_NODES + 255) / 256;
  int base = t * CH;
  int s = 0;
  for(int i=0;i<CH;i++){ int n = base+i; if(n < N_NODES) s += deg[n]; }
  part[t] = s;
  __syncthreads();
  for(int off=1; off<256; off<<=1){
    int v = (t >= off) ? part[t-off] : 0;
    __syncthreads();
    part[t] += v;
    __syncthreads();
  }
  int run = (t==0) ? 0 : part[t-1];
  for(int i=0;i<CH;i++){
    int n = base+i;
    if(n < N_NODES){ row_ptr[n] = run; cursor[n] = run; run += deg[n]; }
  }
  if(t == 255) row_ptr[N_NODES] = run;
}

__global__ void k_scatter(const int* __restrict__ ed, int* __restrict__ cursor, int* __restrict__ eidx){
  int e = blockIdx.x*256 + threadIdx.x;
  if(e < N_EDGES){
    int pos = atomicAdd(&cursor[ed[e]], 1);
    eidx[pos] = e;
  }
}

// ---------------- Layer 1: node transforms (K=4) ----------------
__global__ void k_gemm1(const float* __restrict__ feat, const float* __restrict__ Ws,
                        const float* __restrict__ Wd, float* __restrict__ hs1, float* __restrict__ hd1){
  int idx = blockIdx.x*256 + threadIdx.x;
  if(idx >= N_NODES*D_H1) return;
  int n = idx >> 7, hf = idx & 127;
  float f0 = feat[n*4+0], f1 = feat[n*4+1], f2 = feat[n*4+2], f3 = feat[n*4+3];
  hs1[idx] = f0*Ws[hf] + f1*Ws[128+hf] + f2*Ws[256+hf] + f3*Ws[384+hf];
  hd1[idx] = f0*Wd[hf] + f1*Wd[128+hf] + f2*Wd[256+hf] + f3*Wd[384+hf];
}

// ---------------- Layer 1 fused: scores + online softmax + aggregate + ELU ----------------
// wave per node. element l -> head l>>4; element 64+l -> head 4+(l>>4).
__global__ void k_fused1(const float* __restrict__ hs1, const float* __restrict__ hd1,
                         const int* __restrict__ es, const int* __restrict__ row_ptr,
                         const int* __restrict__ eidx, const float* __restrict__ attn1,
                         float* __restrict__ h1){
  int node = blockIdx.x*4 + (threadIdx.x >> 6);
  int l = threadIdx.x & 63;
  if(node >= N_NODES) return;
  int rp = row_ptr[node], re = row_ptr[node+1];
  float hda = hd1[(size_t)node*D_H1 + l];
  float hdb = hd1[(size_t)node*D_H1 + 64 + l];
  float awa = attn1[l], awb = attn1[64 + l];
  float m0 = -INFINITY, m1 = -INFINITY;
  float d0 = 0.f, d1 = 0.f, a0 = 0.f, a1 = 0.f;
  for(int k=rp; k<re; k++){
    int e = eidx[k]; int s = es[e];
    float hsa = hs1[(size_t)s*D_H1 + l];
    float hsb = hs1[(size_t)s*D_H1 + 64 + l];
    float t0 = leaky1(hsa + hda) * awa;
    float t1 = leaky1(hsb + hdb) * awb;
    #pragma unroll
    for(int off=1; off<16; off<<=1){
      t0 += __shfl_xor(t0, off, 64);
      t1 += __shfl_xor(t1, off, 64);
    }
    // t0 = score(head l>>4), t1 = score(head 4+(l>>4)), uniform within 16-lane group
    float mn0 = fmaxf(m0, t0), mn1 = fmaxf(m1, t1);
    float r0 = expf(m0 - mn0), r1 = expf(m1 - mn1);   // first iter: expf(-inf)=0
    float w0 = expf(t0 - mn0), w1 = expf(t1 - mn1);
    d0 = d0*r0 + w0;           d1 = d1*r1 + w1;
    a0 = a0*r0 + w0*hsa;       a1 = a1*r1 + w1*hsb;
    m0 = mn0;                  m1 = mn1;
  }
  float v0 = a0 / d0, v1 = a1 / d1;
  h1[(size_t)node*D_H1 + l]      = v0 > 0.f ? v0 : expm1f(v0);
  h1[(size_t)node*D_H1 + 64 + l] = v1 > 0.f ? v1 : expm1f(v1);
}

// ---------------- Layer 2: two fused GEMMs (20000x128)@(128x768), fp32 tiled ----------------
// BM=64, BN=128, 256 threads: thread = rg*16+cg computes rows rg*4..+3, cols cg*8..+7, both mats.
__global__ __launch_bounds__(256) void k_gemm2(const float* __restrict__ h1,
                        const float* __restrict__ Ws, const float* __restrict__ Wd,
                        float* __restrict__ hs2, float* __restrict__ hd2){
  __shared__ float At[8][68];     // [kk][row], padded to 68 (272B, 16B-aligned rows)
  __shared__ float Bs[8][128];
  __shared__ float Bd[8][128];
  int m0 = blockIdx.x * 64;
  int c0 = blockIdx.y * 128;
  int tx = threadIdx.x;
  int cg = tx & 15;               // 16 col-groups x 8 cols
  int rg = tx >> 4;               // 16 row-groups x 4 rows
  float acc_s[4][8], acc_d[4][8];
  #pragma unroll
  for(int i=0;i<4;i++)
    #pragma unroll
    for(int j=0;j<8;j++){ acc_s[i][j]=0.f; acc_d[i][j]=0.f; }

  for(int k0=0; k0<D_H1; k0+=8){
    __syncthreads();
    // stage A (transposed): 512 elems, 2/thread; coalesced global, conflict-free LDS write
    #pragma unroll
    for(int i=0;i<2;i++){
      int e = tx + i*256;
      int r = e >> 3, kk = e & 7;
      int row = m0 + r;
      At[kk][r] = (row < N_NODES) ? h1[(size_t)row*D_H1 + k0 + kk] : 0.f;
    }
    // stage B: 1024 elems each, 4/thread, fully coalesced
    #pragma unroll
    for(int i=0;i<4;i++){
      int e = tx + i*256;
      int kk = e >> 7, c = e & 127;
      Bs[kk][c] = Ws[(size_t)(k0+kk)*D_OUT + c0 + c];
      Bd[kk][c] = Wd[(size_t)(k0+kk)*D_OUT + c0 + c];
    }
    __syncthreads();
    #pragma unroll
    for(int kk=0;kk<8;kk++){
      float4 a   = *(const float4*)&At[kk][rg*4];
      float4 bs0 = *(const float4*)&Bs[kk][cg*8];
      float4 bs1 = *(const float4*)&Bs[kk][cg*8+4];
      float4 bd0 = *(const float4*)&Bd[kk][cg*8];
      float4 bd1 = *(const float4*)&Bd[kk][cg*8+4];
      float av[4]  = {a.x, a.y, a.z, a.w};
      float bsv[8] = {bs0.x,bs0.y,bs0.z,bs0.w, bs1.x,bs1.y,bs1.z,bs1.w};
      float bdv[8] = {bd0.x,bd0.y,bd0.z,bd0.w, bd1.x,bd1.y,bd1.z,bd1.w};
      #pragma unroll
      for(int i=0;i<4;i++)
        #pragma unroll
        for(int j=0;j<8;j++){
          acc_s[i][j] += av[i]*bsv[j];
          acc_d[i][j] += av[i]*bdv[j];
        }
    }
  }
  #pragma unroll
  for(int i=0;i<4;i++){
    int row = m0 + rg*4 + i;
    if(row < N_NODES){
      float4 o;
      float* p;
      o.x=acc_s[i][0]; o.y=acc_s[i][1]; o.z=acc_s[i][2]; o.w=acc_s[i][3];
      p = &hs2[(size_t)row*D_OUT + c0 + cg*8];     *(float4*)p = o;
      o.x=acc_s[i][4]; o.y=acc_s[i][5]; o.z=acc_s[i][6]; o.w=acc_s[i][7];
      *(float4*)(p+4) = o;
      o.x=acc_d[i][0]; o.y=acc_d[i][1]; o.z=acc_d[i][2]; o.w=acc_d[i][3];
      p = &hd2[(size_t)row*D_OUT + c0 + cg*8];     *(float4*)p = o;
      o.x=acc_d[i][4]; o.y=acc_d[i][5]; o.z=acc_d[i][6]; o.w=acc_d[i][7];
      *(float4*)(p+4) = o;
    }
  }
}

// ---------------- Layer 2 fused: scores + online softmax + aggregate ----------------
// wave per node: hd2[node] row cached in 12 float4 regs, hs2[src] read ONCE per edge.
__global__ void k_fused2(const float* __restrict__ hs2, const float* __restrict__ hd2,
                         const int* __restrict__ es, const int* __restrict__ row_ptr,
                         const int* __restrict__ eidx, const float* __restrict__ attn2,
                         float* __restrict__ h2){
  int node = blockIdx.x*4 + (threadIdx.x >> 6);
  int l = threadIdx.x & 63;
  if(node >= N_NODES) return;
  int rp = row_ptr[node], re = row_ptr[node+1];
  const float4* pd = (const float4*)(hd2 + (size_t)node*D_OUT);
  const float4* pa = (const float4*)attn2;
  float4 hd0 = pd[l], hd1v = pd[64+l], hd2v = pd[128+l];
  float4 aw0 = pa[l], aw1  = pa[64+l], aw2  = pa[128+l];
  float m = -INFINITY, den = 0.f;
  float4 ac0 = make_float4(0,0,0,0), ac1 = make_float4(0,0,0,0), ac2 = make_float4(0,0,0,0);
  for(int k=rp; k<re; k++){
    int e = eidx[k]; int s = es[e];
    const float4* ps = (const float4*)(hs2 + (size_t)s*D_OUT);
    float4 v0 = ps[l], v1 = ps[64+l], v2 = ps[128+l];
    float sc = leaky1(v0.x+hd0.x)*aw0.x + leaky1(v0.y+hd0.y)*aw0.y
             + leaky1(v0.z+hd0.z)*aw0.z + leaky1(v0.w+hd0.w)*aw0.w
             + leaky1(v1.x+hd1v.x)*aw1.x + leaky1(v1.y+hd1v.y)*aw1.y
             + leaky1(v1.z+hd1v.z)*aw1.z + leaky1(v1.w+hd1v.w)*aw1.w
             + leaky1(v2.x+hd2v.x)*aw2.x + leaky1(v2.y+hd2v.y)*aw2.y
             + leaky1(v2.z+hd2v.z)*aw2.z + leaky1(v2.w+hd2v.w)*aw2.w;
    #pragma unroll
    for(int off=1; off<64; off<<=1) sc += __shfl_xor(sc, off, 64);
    float mn = fmaxf(m, sc);
    float r = expf(m - mn);            // first iter: expf(-inf)=0
    float w = expf(sc - mn);
    den = den*r + w;
    ac0.x = ac0.x*r + w*v0.x; ac0.y = ac0.y*r + w*v0.y;
    ac0.z = ac0.z*r + w*v0.z; ac0.w = ac0.w*r + w*v0.w;
    ac1.x = ac1.x*r + w*v1.x; ac1.y = ac1.y*r + w*v1.y;
    ac1.z = ac1.z*r + w*v1.z; ac1.w = ac1.w*r + w*v1.w;
    ac2.x = ac2.x*r + w*v2.x; ac2.y = ac2.y*r + w*v2.y;
    ac2.z = ac2.z*r + w*v2.z; ac2.w = ac2.w*r + w*v2.w;
    m = mn;
  }
  float rd = 1.f/den;
  float4* po = (float4*)(h2 + (size_t)node*D_OUT);
  ac0.x*=rd; ac0.y*=rd; ac0.z*=rd; ac0.w*=rd;
  ac1.x*=rd; ac1.y*=rd; ac1.z*=rd; ac1.w*=rd;
  ac2.x*=rd; ac2.y*=rd; ac2.z*=rd; ac2.w*=rd;
  po[l] = ac0; po[64+l] = ac1; po[128+l] = ac2;
}

// ---------------- Output assembly: gathers + positional embedding ----------------
__global__ __launch_bounds__(192) void k_out(const float* __restrict__ h2,
    const int* __restrict__ tok, const int* __restrict__ mins, const int* __restrict__ wkd,
    const int* __restrict__ dayl, const int* __restrict__ grd,
    const float* __restrict__ grid_t, const float* __restrict__ dayt_t,
    const float* __restrict__ week_t, const float* __restrict__ day_t,
    float* __restrict__ out){
  int bs = blockIdx.x;
  int t  = threadIdx.x;
  int s  = bs & (S_LEN-1);
  int tk = tok[bs], mn = mins[bs], wk = wkd[bs], dy = dayl[bs], gr = grd[bs];
  float4 r = ((const float4*)(h2 + (size_t)tk*D_OUT))[t];
  float4 v;
  v = ((const float4*)(week_t + (size_t)wk*D_OUT))[t]; r.x+=v.x; r.y+=v.y; r.z+=v.z; r.w+=v.w;
  v = ((const float4*)(dayt_t + (size_t)mn*D_OUT))[t]; r.x+=v.x; r.y+=v.y; r.z+=v.z; r.w+=v.w;
  v = ((const float4*)(day_t  + (size_t)dy*D_OUT))[t]; r.x+=v.x; r.y+=v.y; r.z+=v.z; r.w+=v.w;
  v = ((const float4*)(grid_t + (size_t)gr*D_OUT))[t]; r.x+=v.x; r.y+=v.y; r.z+=v.z; r.w+=v.w;
  const float K = 0.011992630692677313f;   // ln(10000)/768
  float d0 = expf(-K * (float)(4*t));
  float d1 = expf(-K * (float)(4*t+2));
  float sf = (float)s;
  r.x += sinf(sf*d0); r.y += cosf(sf*d0);
  r.z += sinf(sf*d1); r.w += cosf(sf*d1);
  ((float4*)(out + (size_t)bs*D_OUT))[t] = r;
}

extern "C" void kernel_launch(void* const* d_in, const int* in_sizes, int n_in,
                              void* d_out, int out_size, void* d_ws, size_t ws_size,
                              hipStream_t stream) {
  const int*   trj   = (const int*)  d_in[0];
  const int*   mins  = (const int*)  d_in[1];
  const int*   wkd   = (const int*)  d_in[2];
  const int*   dayl  = (const int*)  d_in[3];
  const int*   grd   = (const int*)  d_in[4];
  const int*   es    = (const int*)  d_in[6];
  const int*   ed    = (const int*)  d_in[7];
  const float* feat  = (const float*)d_in[8];
  const float* Ws1   = (const float*)d_in[9];
  const float* Wd1   = (const float*)d_in[10];
  const float* attn1 = (const float*)d_in[11];
  const float* Ws2   = (const float*)d_in[12];
  const float* Wd2   = (const float*)d_in[13];
  const float* attn2 = (const float*)d_in[14];
  const float* gridt = (const float*)d_in[15];
  const float* daytt = (const float*)d_in[16];
  const float* weekt = (const float*)d_in[17];
  const float* dayt  = (const float*)d_in[18];
  float* out = (float*)d_out;

  char* ws = (char*)d_ws;
  size_t off = 0;
  auto alloc = [&](size_t bytes)->char*{
    char* p = ws + off;
    off += bytes;
    off = (off + 255) & ~(size_t)255;
    return p;
  };
  float* hs1    = (float*)alloc((size_t)N_NODES*D_H1*4);
  float* hd1    = (float*)alloc((size_t)N_NODES*D_H1*4);
  float* h1     = (float*)alloc((size_t)N_NODES*D_H1*4);
  float* hs2    = (float*)alloc((size_t)N_NODES*D_OUT*4);
  float* hd2    = (float*)alloc((size_t)N_NODES*D_OUT*4);
  float* h2     = (float*)alloc((size_t)N_NODES*D_OUT*4);
  int* deg      = (int*)alloc((size_t)N_NODES*4);
  int* row_ptr  = (int*)alloc((size_t)(N_NODES+1)*4);
  int* cursor   = (int*)alloc((size_t)N_NODES*4);
  int* eidx     = (int*)alloc((size_t)N_EDGES*4);

  // CSR by destination (ws re-poisoned each run -> must zero deg)
  hipMemsetAsync(deg, 0, (size_t)N_NODES*4, stream);
  k_count  <<<(N_EDGES+255)/256, 256, 0, stream>>>(ed, deg);
  k_scan   <<<1, 256, 0, stream>>>(deg, row_ptr, cursor);
  k_scatter<<<(N_EDGES+255)/256, 256, 0, stream>>>(ed, cursor, eidx);

  // Layer 1
  k_gemm1 <<<(N_NODES*D_H1)/256, 256, 0, stream>>>(feat, Ws1, Wd1, hs1, hd1);
  k_fused1<<<(N_NODES+3)/4, 256, 0, stream>>>(hs1, hd1, es, row_ptr, eidx, attn1, h1);

  // Layer 2
  dim3 g2((N_NODES+63)/64, D_OUT/128);
  k_gemm2 <<<g2, 256, 0, stream>>>(h1, Ws2, Wd2, hs2, hd2);
  k_fused2<<<(N_NODES+3)/4, 256, 0, stream>>>(hs2, hd2, es, row_ptr, eidx, attn2, h2);

  // Output
  k_out<<<B_SZ*S_LEN, 192, 0, stream>>>(h2, trj, mins, wkd, dayl, grd,
                                        gridt, daytt, weekt, dayt, out);
}

// Round 7
// 422.061 us; speedup vs baseline: 1.7263x; 1.1531x over previous
//
#include <hip/hip_runtime.h>
#include <hip/hip_bf16.h>

#define N_NODES 20000
#define N_EDGES 180000
#define D_OUT   768
#define D_H1    128
#define B_SZ    16
#define S_LEN   512
#define NEG_SLOPE_C 0.2f

__device__ __forceinline__ float leaky1(float x){ return x >= 0.0f ? x : NEG_SLOPE_C * x; }
__device__ __forceinline__ unsigned short f2bf(float x){
  union { __hip_bfloat16 h; unsigned short u; } v; v.h = __float2bfloat16(x); return v.u;
}
__device__ __forceinline__ float bf2f(unsigned short u){
  return __uint_as_float(((unsigned)u) << 16);
}
__device__ __forceinline__ float4 bf4_to_f4(ushort4 u){
  return make_float4(bf2f(u.x), bf2f(u.y), bf2f(u.z), bf2f(u.w));
}

// ---------------- CSR build (by destination) ----------------
__global__ void k_count(const int* __restrict__ ed, int* __restrict__ deg){
  int e = blockIdx.x*256 + threadIdx.x;
  if(e < N_EDGES) atomicAdd(&deg[ed[e]], 1);
}

__global__ void k_scan(const int* __restrict__ deg, int* __restrict__ row_ptr, int* __restrict__ cursor){
  __shared__ int part[256];
  int t = threadIdx.x;
  const int CH = (N_NODES + 255) / 256;
  int base = t * CH;
  int s = 0;
  for(int i=0;i<CH;i++){ int n = base+i; if(n < N_NODES) s += deg[n]; }
  part[t] = s;
  __syncthreads();
  for(int off=1; off<256; off<<=1){
    int v = (t >= off) ? part[t-off] : 0;
    __syncthreads();
    part[t] += v;
    __syncthreads();
  }
  int run = (t==0) ? 0 : part[t-1];
  for(int i=0;i<CH;i++){
    int n = base+i;
    if(n < N_NODES){ row_ptr[n] = run; cursor[n] = run; run += deg[n]; }
  }
  if(t == 255) row_ptr[N_NODES] = run;
}

__global__ void k_scatter(const int* __restrict__ ed, int* __restrict__ cursor, int* __restrict__ eidx){
  int e = blockIdx.x*256 + threadIdx.x;
  if(e < N_EDGES){
    int pos = atomicAdd(&cursor[ed[e]], 1);
    eidx[pos] = e;
  }
}

// ---------------- Layer 1: node transforms (K=4), bf16 outputs ----------------
__global__ void k_gemm1(const float* __restrict__ feat, const float* __restrict__ Ws,
                        const float* __restrict__ Wd,
                        unsigned short* __restrict__ hs1, unsigned short* __restrict__ hd1){
  int idx = blockIdx.x*256 + threadIdx.x;
  if(idx >= N_NODES*D_H1) return;
  int n = idx >> 7, hf = idx & 127;
  float f0 = feat[n*4+0], f1 = feat[n*4+1], f2 = feat[n*4+2], f3 = feat[n*4+3];
  hs1[idx] = f2bf(f0*Ws[hf] + f1*Ws[128+hf] + f2*Ws[256+hf] + f3*Ws[384+hf]);
  hd1[idx] = f2bf(f0*Wd[hf] + f1*Wd[128+hf] + f2*Wd[256+hf] + f3*Wd[384+hf]);
}

// ---------------- Layer 1 fused: scores + online softmax + aggregate + ELU ----------------
__global__ void k_fused1(const unsigned short* __restrict__ hs1, const unsigned short* __restrict__ hd1,
                         const int* __restrict__ es, const int* __restrict__ row_ptr,
                         const int* __restrict__ eidx, const float* __restrict__ attn1,
                         float* __restrict__ h1){
  int node = blockIdx.x*4 + (threadIdx.x >> 6);
  int l = threadIdx.x & 63;
  if(node >= N_NODES) return;
  int rp = row_ptr[node], re = row_ptr[node+1];
  float hda = bf2f(hd1[(size_t)node*D_H1 + l]);
  float hdb = bf2f(hd1[(size_t)node*D_H1 + 64 + l]);
  float awa = attn1[l], awb = attn1[64 + l];
  float m0 = -INFINITY, m1 = -INFINITY;
  float d0 = 0.f, d1 = 0.f, a0 = 0.f, a1 = 0.f;
  for(int k=rp; k<re; k++){
    int e = eidx[k]; int s = es[e];
    float hsa = bf2f(hs1[(size_t)s*D_H1 + l]);
    float hsb = bf2f(hs1[(size_t)s*D_H1 + 64 + l]);
    float t0 = leaky1(hsa + hda) * awa;
    float t1 = leaky1(hsb + hdb) * awb;
    #pragma unroll
    for(int off=1; off<16; off<<=1){
      t0 += __shfl_xor(t0, off, 64);
      t1 += __shfl_xor(t1, off, 64);
    }
    float mn0 = fmaxf(m0, t0), mn1 = fmaxf(m1, t1);
    float r0 = expf(m0 - mn0), r1 = expf(m1 - mn1);
    float w0 = expf(t0 - mn0), w1 = expf(t1 - mn1);
    d0 = d0*r0 + w0;           d1 = d1*r1 + w1;
    a0 = a0*r0 + w0*hsa;       a1 = a1*r1 + w1*hsb;
    m0 = mn0;                  m1 = mn1;
  }
  float v0 = a0 / d0, v1 = a1 / d1;
  h1[(size_t)node*D_H1 + l]      = v0 > 0.f ? v0 : expm1f(v0);
  h1[(size_t)node*D_H1 + 64 + l] = v1 > 0.f ? v1 : expm1f(v1);
}

// ---------------- Layer 2: two fused GEMMs (20000x128)@(128x768) ----------------
// BM=128, BN=128, 256 thr; thread(rg,cg): rows rg*8..+7, cols {cg*4..+3, 64+cg*4..+3}, both mats.
// LDS reads: A broadcast (free), B stride-4 lanes -> 2-way bank alias (free per m136).
__global__ __launch_bounds__(256,2) void k_gemm2(const float* __restrict__ h1,
                        const float* __restrict__ Ws, const float* __restrict__ Wd,
                        unsigned short* __restrict__ hs2, unsigned short* __restrict__ hd2){
  __shared__ float At[8][136];   // [kk][row], stride 136: kk-rows offset by 8 banks
  __shared__ float Bs[8][128];
  __shared__ float Bd[8][128];
  int m0 = blockIdx.x * 128;
  int c0 = blockIdx.y * 128;
  int tx = threadIdx.x;
  int cg = tx & 15;
  int rg = tx >> 4;
  float acc_s[8][8], acc_d[8][8];
  #pragma unroll
  for(int i=0;i<8;i++)
    #pragma unroll
    for(int j=0;j<8;j++){ acc_s[i][j]=0.f; acc_d[i][j]=0.f; }

  for(int k0=0; k0<D_H1; k0+=8){
    __syncthreads();
    { // stage A: 128 rows x 8 k, one float4 per thread, transposed into At
      int r = tx >> 1, kh = tx & 1;
      int row = m0 + r;
      float4 a = (row < N_NODES) ? *(const float4*)&h1[(size_t)row*D_H1 + k0 + kh*4]
                                 : make_float4(0.f,0.f,0.f,0.f);
      At[kh*4+0][r] = a.x; At[kh*4+1][r] = a.y; At[kh*4+2][r] = a.z; At[kh*4+3][r] = a.w;
    }
    { // stage B: 8 k x 128 cols per mat, one float4 per thread per mat
      int kk = tx >> 5, c4 = (tx & 31) * 4;
      *(float4*)&Bs[kk][c4] = *(const float4*)&Ws[(size_t)(k0+kk)*D_OUT + c0 + c4];
      *(float4*)&Bd[kk][c4] = *(const float4*)&Wd[(size_t)(k0+kk)*D_OUT + c0 + c4];
    }
    __syncthreads();
    #pragma unroll
    for(int kk=0;kk<8;kk++){
      float4 a0 = *(const float4*)&At[kk][rg*8];
      float4 a1 = *(const float4*)&At[kk][rg*8+4];
      float4 b0 = *(const float4*)&Bs[kk][cg*4];
      float4 b1 = *(const float4*)&Bs[kk][64+cg*4];
      float4 e0 = *(const float4*)&Bd[kk][cg*4];
      float4 e1 = *(const float4*)&Bd[kk][64+cg*4];
      float av[8]  = {a0.x,a0.y,a0.z,a0.w,a1.x,a1.y,a1.z,a1.w};
      float bsv[8] = {b0.x,b0.y,b0.z,b0.w,b1.x,b1.y,b1.z,b1.w};
      float bdv[8] = {e0.x,e0.y,e0.z,e0.w,e1.x,e1.y,e1.z,e1.w};
      #pragma unroll
      for(int i=0;i<8;i++)
        #pragma unroll
        for(int j=0;j<8;j++){
          acc_s[i][j] += av[i]*bsv[j];
          acc_d[i][j] += av[i]*bdv[j];
        }
    }
  }
  #pragma unroll
  for(int i=0;i<8;i++){
    int row = m0 + rg*8 + i;
    if(row < N_NODES){
      size_t base = (size_t)row*D_OUT + c0;
      ushort4 u;
      u.x=f2bf(acc_s[i][0]); u.y=f2bf(acc_s[i][1]); u.z=f2bf(acc_s[i][2]); u.w=f2bf(acc_s[i][3]);
      *(ushort4*)&hs2[base + cg*4] = u;
      u.x=f2bf(acc_s[i][4]); u.y=f2bf(acc_s[i][5]); u.z=f2bf(acc_s[i][6]); u.w=f2bf(acc_s[i][7]);
      *(ushort4*)&hs2[base + 64 + cg*4] = u;
      u.x=f2bf(acc_d[i][0]); u.y=f2bf(acc_d[i][1]); u.z=f2bf(acc_d[i][2]); u.w=f2bf(acc_d[i][3]);
      *(ushort4*)&hd2[base + cg*4] = u;
      u.x=f2bf(acc_d[i][4]); u.y=f2bf(acc_d[i][5]); u.z=f2bf(acc_d[i][6]); u.w=f2bf(acc_d[i][7]);
      *(ushort4*)&hd2[base + 64 + cg*4] = u;
    }
  }
}

// ---------------- Layer 2 fused: scores + online softmax + aggregate ----------------
// wave per node; hd2[node] cached in regs; hs2[src] (bf16) read ONCE per edge.
__global__ void k_fused2(const unsigned short* __restrict__ hs2, const unsigned short* __restrict__ hd2,
                         const int* __restrict__ es, const int* __restrict__ row_ptr,
                         const int* __restrict__ eidx, const float* __restrict__ attn2,
                         float* __restrict__ h2){
  int node = blockIdx.x*4 + (threadIdx.x >> 6);
  int l = threadIdx.x & 63;
  if(node >= N_NODES) return;
  int rp = row_ptr[node], re = row_ptr[node+1];
  const ushort4* pd = (const ushort4*)(hd2 + (size_t)node*D_OUT);
  const float4*  pa = (const float4*)attn2;
  float4 hd0 = bf4_to_f4(pd[l]), hd1v = bf4_to_f4(pd[64+l]), hd2v = bf4_to_f4(pd[128+l]);
  float4 aw0 = pa[l], aw1 = pa[64+l], aw2 = pa[128+l];
  float m = -INFINITY, den = 0.f;
  float4 ac0 = make_float4(0,0,0,0), ac1 = make_float4(0,0,0,0), ac2 = make_float4(0,0,0,0);
  for(int k=rp; k<re; k++){
    int e = eidx[k]; int s = es[e];
    const ushort4* ps = (const ushort4*)(hs2 + (size_t)s*D_OUT);
    float4 v0 = bf4_to_f4(ps[l]), v1 = bf4_to_f4(ps[64+l]), v2 = bf4_to_f4(ps[128+l]);
    float sc = leaky1(v0.x+hd0.x)*aw0.x + leaky1(v0.y+hd0.y)*aw0.y
             + leaky1(v0.z+hd0.z)*aw0.z + leaky1(v0.w+hd0.w)*aw0.w
             + leaky1(v1.x+hd1v.x)*aw1.x + leaky1(v1.y+hd1v.y)*aw1.y
             + leaky1(v1.z+hd1v.z)*aw1.z + leaky1(v1.w+hd1v.w)*aw1.w
             + leaky1(v2.x+hd2v.x)*aw2.x + leaky1(v2.y+hd2v.y)*aw2.y
             + leaky1(v2.z+hd2v.z)*aw2.z + leaky1(v2.w+hd2v.w)*aw2.w;
    #pragma unroll
    for(int off=1; off<64; off<<=1) sc += __shfl_xor(sc, off, 64);
    float mn = fmaxf(m, sc);
    float r = expf(m - mn);
    float w = expf(sc - mn);
    den = den*r + w;
    ac0.x = ac0.x*r + w*v0.x; ac0.y = ac0.y*r + w*v0.y;
    ac0.z = ac0.z*r + w*v0.z; ac0.w = ac0.w*r + w*v0.w;
    ac1.x = ac1.x*r + w*v1.x; ac1.y = ac1.y*r + w*v1.y;
    ac1.z = ac1.z*r + w*v1.z; ac1.w = ac1.w*r + w*v1.w;
    ac2.x = ac2.x*r + w*v2.x; ac2.y = ac2.y*r + w*v2.y;
    ac2.z = ac2.z*r + w*v2.z; ac2.w = ac2.w*r + w*v2.w;
    m = mn;
  }
  float rd = 1.f/den;
  float4* po = (float4*)(h2 + (size_t)node*D_OUT);
  ac0.x*=rd; ac0.y*=rd; ac0.z*=rd; ac0.w*=rd;
  ac1.x*=rd; ac1.y*=rd; ac1.z*=rd; ac1.w*=rd;
  ac2.x*=rd; ac2.y*=rd; ac2.z*=rd; ac2.w*=rd;
  po[l] = ac0; po[64+l] = ac1; po[128+l] = ac2;
}

// ---------------- Output assembly ----------------
__global__ __launch_bounds__(192) void k_out(const float* __restrict__ h2,
    const int* __restrict__ tok, const int* __restrict__ mins, const int* __restrict__ wkd,
    const int* __restrict__ dayl, const int* __restrict__ grd,
    const float* __restrict__ grid_t, const float* __restrict__ dayt_t,
    const float* __restrict__ week_t, const float* __restrict__ day_t,
    float* __restrict__ out){
  int bs = blockIdx.x;
  int t  = threadIdx.x;
  int s  = bs & (S_LEN-1);
  int tk = tok[bs], mn = mins[bs], wk = wkd[bs], dy = dayl[bs], gr = grd[bs];
  float4 r = ((const float4*)(h2 + (size_t)tk*D_OUT))[t];
  float4 v;
  v = ((const float4*)(week_t + (size_t)wk*D_OUT))[t]; r.x+=v.x; r.y+=v.y; r.z+=v.z; r.w+=v.w;
  v = ((const float4*)(dayt_t + (size_t)mn*D_OUT))[t]; r.x+=v.x; r.y+=v.y; r.z+=v.z; r.w+=v.w;
  v = ((const float4*)(day_t  + (size_t)dy*D_OUT))[t]; r.x+=v.x; r.y+=v.y; r.z+=v.z; r.w+=v.w;
  v = ((const float4*)(grid_t + (size_t)gr*D_OUT))[t]; r.x+=v.x; r.y+=v.y; r.z+=v.z; r.w+=v.w;
  const float K = 0.011992630692677313f;   // ln(10000)/768
  float d0 = expf(-K * (float)(4*t));
  float d1 = expf(-K * (float)(4*t+2));
  float sf = (float)s;
  r.x += sinf(sf*d0); r.y += cosf(sf*d0);
  r.z += sinf(sf*d1); r.w += cosf(sf*d1);
  ((float4*)(out + (size_t)bs*D_OUT))[t] = r;
}

extern "C" void kernel_launch(void* const* d_in, const int* in_sizes, int n_in,
                              void* d_out, int out_size, void* d_ws, size_t ws_size,
                              hipStream_t stream) {
  const int*   trj   = (const int*)  d_in[0];
  const int*   mins  = (const int*)  d_in[1];
  const int*   wkd   = (const int*)  d_in[2];
  const int*   dayl  = (const int*)  d_in[3];
  const int*   grd   = (const int*)  d_in[4];
  const int*   es    = (const int*)  d_in[6];
  const int*   ed    = (const int*)  d_in[7];
  const float* feat  = (const float*)d_in[8];
  const float* Ws1   = (const float*)d_in[9];
  const float* Wd1   = (const float*)d_in[10];
  const float* attn1 = (const float*)d_in[11];
  const float* Ws2   = (const float*)d_in[12];
  const float* Wd2   = (const float*)d_in[13];
  const float* attn2 = (const float*)d_in[14];
  const float* gridt = (const float*)d_in[15];
  const float* daytt = (const float*)d_in[16];
  const float* weekt = (const float*)d_in[17];
  const float* dayt  = (const float*)d_in[18];
  float* out = (float*)d_out;

  char* ws = (char*)d_ws;
  size_t off = 0;
  auto alloc = [&](size_t bytes)->char*{
    char* p = ws + off;
    off += bytes;
    off = (off + 255) & ~(size_t)255;
    return p;
  };
  unsigned short* hs1 = (unsigned short*)alloc((size_t)N_NODES*D_H1*2);
  unsigned short* hd1 = (unsigned short*)alloc((size_t)N_NODES*D_H1*2);
  float*          h1  = (float*)         alloc((size_t)N_NODES*D_H1*4);
  unsigned short* hs2 = (unsigned short*)alloc((size_t)N_NODES*D_OUT*2);
  unsigned short* hd2 = (unsigned short*)alloc((size_t)N_NODES*D_OUT*2);
  float*          h2  = (float*)         alloc((size_t)N_NODES*D_OUT*4);
  int* deg      = (int*)alloc((size_t)N_NODES*4);
  int* row_ptr  = (int*)alloc((size_t)(N_NODES+1)*4);
  int* cursor   = (int*)alloc((size_t)N_NODES*4);
  int* eidx     = (int*)alloc((size_t)N_EDGES*4);

  // CSR by destination (ws re-poisoned each run -> must zero deg)
  hipMemsetAsync(deg, 0, (size_t)N_NODES*4, stream);
  k_count  <<<(N_EDGES+255)/256, 256, 0, stream>>>(ed, deg);
  k_scan   <<<1, 256, 0, stream>>>(deg, row_ptr, cursor);
  k_scatter<<<(N_EDGES+255)/256, 256, 0, stream>>>(ed, cursor, eidx);

  // Layer 1
  k_gemm1 <<<(N_NODES*D_H1)/256, 256, 0, stream>>>(feat, Ws1, Wd1, hs1, hd1);
  k_fused1<<<(N_NODES+3)/4, 256, 0, stream>>>(hs1, hd1, es, row_ptr, eidx, attn1, h1);

  // Layer 2
  dim3 g2((N_NODES+127)/128, D_OUT/128);
  k_gemm2 <<<g2, 256, 0, stream>>>(h1, Ws2, Wd2, hs2, hd2);
  k_fused2<<<(N_NODES+3)/4, 256, 0, stream>>>(hs2, hd2, es, row_ptr, eidx, attn2, h2);

  // Output
  k_out<<<B_SZ*S_LEN, 192, 0, stream>>>(h2, trj, mins, wkd, dayl, grd,
                                        gridt, daytt, weekt, dayt, out);
}

// Round 9
// 374.936 us; speedup vs baseline: 1.9433x; 1.1257x over previous
//
#include <hip/hip_runtime.h>
#include <hip/hip_bf16.h>

#define N_NODES 20000
#define N_EDGES 180000
#define D_OUT   768
#define D_H1    128
#define B_SZ    16
#define S_LEN   512
#define NEG_SLOPE_C 0.2f

typedef __attribute__((ext_vector_type(8))) short bf16x8;   // 8 bf16 = 4 VGPRs
typedef __attribute__((ext_vector_type(4))) float f32x4;    // MFMA acc

__device__ __forceinline__ float leaky1(float x){ return x >= 0.0f ? x : NEG_SLOPE_C * x; }
__device__ __forceinline__ unsigned short f2bf(float x){
  union { __hip_bfloat16 h; unsigned short u; } v; v.h = __float2bfloat16(x); return v.u;
}
__device__ __forceinline__ float bf2f(unsigned short u){
  return __uint_as_float(((unsigned)u) << 16);
}
__device__ __forceinline__ float4 bf4_to_f4(ushort4 u){
  return make_float4(bf2f(u.x), bf2f(u.y), bf2f(u.z), bf2f(u.w));
}

// ---------------- CSR build (by destination) ----------------
__global__ void k_count(const int* __restrict__ ed, int* __restrict__ deg){
  int e = blockIdx.x*256 + threadIdx.x;
  if(e < N_EDGES) atomicAdd(&deg[ed[e]], 1);
}

__global__ void k_scan(const int* __restrict__ deg, int* __restrict__ row_ptr, int* __restrict__ cursor){
  __shared__ int part[256];
  int t = threadIdx.x;
  const int CH = (N_NODES + 255) / 256;
  int base = t * CH;
  int s = 0;
  for(int i=0;i<CH;i++){ int n = base+i; if(n < N_NODES) s += deg[n]; }
  part[t] = s;
  __syncthreads();
  for(int off=1; off<256; off<<=1){
    int v = (t >= off) ? part[t-off] : 0;
    __syncthreads();
    part[t] += v;
    __syncthreads();
  }
  int run = (t==0) ? 0 : part[t-1];
  for(int i=0;i<CH;i++){
    int n = base+i;
    if(n < N_NODES){ row_ptr[n] = run; cursor[n] = run; run += deg[n]; }
  }
  if(t == 255) row_ptr[N_NODES] = run;
}

__global__ void k_scatter(const int* __restrict__ ed, int* __restrict__ cursor, int* __restrict__ eidx){
  int e = blockIdx.x*256 + threadIdx.x;
  if(e < N_EDGES){
    int pos = atomicAdd(&cursor[ed[e]], 1);
    eidx[pos] = e;
  }
}

// ---------------- Layer 1: node transforms (K=4), bf16 outputs ----------------
__global__ void k_gemm1(const float* __restrict__ feat, const float* __restrict__ Ws,
                        const float* __restrict__ Wd,
                        unsigned short* __restrict__ hs1, unsigned short* __restrict__ hd1){
  int idx = blockIdx.x*256 + threadIdx.x;
  if(idx >= N_NODES*D_H1) return;
  int n = idx >> 7, hf = idx & 127;
  float f0 = feat[n*4+0], f1 = feat[n*4+1], f2 = feat[n*4+2], f3 = feat[n*4+3];
  hs1[idx] = f2bf(f0*Ws[hf] + f1*Ws[128+hf] + f2*Ws[256+hf] + f3*Ws[384+hf]);
  hd1[idx] = f2bf(f0*Wd[hf] + f1*Wd[128+hf] + f2*Wd[256+hf] + f3*Wd[384+hf]);
}

// ---------------- Layer 1 fused: scores + online softmax + aggregate + ELU (bf16 out) ----------------
__global__ void k_fused1(const unsigned short* __restrict__ hs1, const unsigned short* __restrict__ hd1,
                         const int* __restrict__ es, const int* __restrict__ row_ptr,
                         const int* __restrict__ eidx, const float* __restrict__ attn1,
                         unsigned short* __restrict__ h1){
  int node = blockIdx.x*4 + (threadIdx.x >> 6);
  int l = threadIdx.x & 63;
  if(node >= N_NODES) return;
  int rp = row_ptr[node], re = row_ptr[node+1];
  float hda = bf2f(hd1[(size_t)node*D_H1 + l]);
  float hdb = bf2f(hd1[(size_t)node*D_H1 + 64 + l]);
  float awa = attn1[l], awb = attn1[64 + l];
  float m0 = -INFINITY, m1 = -INFINITY;
  float d0 = 0.f, d1 = 0.f, a0 = 0.f, a1 = 0.f;
  for(int k=rp; k<re; k++){
    int e = eidx[k]; int s = es[e];
    float hsa = bf2f(hs1[(size_t)s*D_H1 + l]);
    float hsb = bf2f(hs1[(size_t)s*D_H1 + 64 + l]);
    float t0 = leaky1(hsa + hda) * awa;
    float t1 = leaky1(hsb + hdb) * awb;
    #pragma unroll
    for(int off=1; off<16; off<<=1){
      t0 += __shfl_xor(t0, off, 64);
      t1 += __shfl_xor(t1, off, 64);
    }
    float mn0 = fmaxf(m0, t0), mn1 = fmaxf(m1, t1);
    float r0 = expf(m0 - mn0), r1 = expf(m1 - mn1);
    float w0 = expf(t0 - mn0), w1 = expf(t1 - mn1);
    d0 = d0*r0 + w0;           d1 = d1*r1 + w1;
    a0 = a0*r0 + w0*hsa;       a1 = a1*r1 + w1*hsb;
    m0 = mn0;                  m1 = mn1;
  }
  float v0 = a0 / d0, v1 = a1 / d1;
  v0 = v0 > 0.f ? v0 : expm1f(v0);
  v1 = v1 > 0.f ? v1 : expm1f(v1);
  h1[(size_t)node*D_H1 + l]      = f2bf(v0);
  h1[(size_t)node*D_H1 + 64 + l] = f2bf(v1);
}

// ---------------- W2 prep: fp32 [k][768] -> bf16 transposed [col][k] ----------------
__global__ void k_wprep(const float* __restrict__ Ws, const float* __restrict__ Wd,
                        unsigned short* __restrict__ WtS, unsigned short* __restrict__ WtD){
  int i = blockIdx.x*256 + threadIdx.x;   // over 768*128
  if(i >= D_OUT*D_H1) return;
  int c = i >> 7, k = i & 127;
  WtS[i] = f2bf(Ws[(size_t)k*D_OUT + c]);
  WtD[i] = f2bf(Wd[(size_t)k*D_OUT + c]);
}

// ---------------- Layer 2: MFMA bf16 GEMM (20000x128)@(128x768), both mats ----------------
// 256 thr = 4 waves (2x2). Wave tile: 32 rows x 64 cols x 2 mats = 16 f32x4 accs.
// A frag: row=lane&15, k=8*(lane>>4)+i  -> contiguous ushort8 from bf16 h1 (row-major).
// B frag: col=lane&15, k=8*(lane>>4)+i  -> contiguous ushort8 from Wt (col-major = W^T).
// C/D:    col=lane&15, row=(lane>>4)*4+reg   [m89-verified layout]
__global__ __launch_bounds__(256) void k_gemm2m(const unsigned short* __restrict__ h1b,
                        const unsigned short* __restrict__ WtS, const unsigned short* __restrict__ WtD,
                        unsigned short* __restrict__ hs2, unsigned short* __restrict__ hd2){
  int wave = threadIdx.x >> 6, lane = threadIdx.x & 63;
  int wr = wave >> 1, wc = wave & 1;
  int m0 = blockIdx.x*64 + wr*32;
  int c0 = blockIdx.y*128 + wc*64;
  int lr = lane & 15, lk = lane >> 4;

  f32x4 acc[2][4][2];
  #pragma unroll
  for(int a=0;a<2;a++)
    #pragma unroll
    for(int j=0;j<4;j++)
      #pragma unroll
      for(int mmat=0;mmat<2;mmat++)
        acc[a][j][mmat] = (f32x4){0.f,0.f,0.f,0.f};

  // clamp A row reads (stores are guarded)
  int ra0 = m0 + lr;      if(ra0 > N_NODES-1) ra0 = N_NODES-1;
  int ra1 = m0 + 16 + lr; if(ra1 > N_NODES-1) ra1 = N_NODES-1;
  const unsigned short* pa0 = h1b + (size_t)ra0*D_H1 + lk*8;
  const unsigned short* pa1 = h1b + (size_t)ra1*D_H1 + lk*8;

  #pragma unroll
  for(int t=0;t<4;t++){              // K = 4 x 32
    bf16x8 a0 = *(const bf16x8*)(pa0 + t*32);
    bf16x8 a1 = *(const bf16x8*)(pa1 + t*32);
    #pragma unroll
    for(int j=0;j<4;j++){
      size_t bo = (size_t)(c0 + j*16 + lr)*D_H1 + t*32 + lk*8;
      bf16x8 bs = *(const bf16x8*)(WtS + bo);
      bf16x8 bd = *(const bf16x8*)(WtD + bo);
      acc[0][j][0] = __builtin_amdgcn_mfma_f32_16x16x32_bf16(a0, bs, acc[0][j][0], 0, 0, 0);
      acc[1][j][0] = __builtin_amdgcn_mfma_f32_16x16x32_bf16(a1, bs, acc[1][j][0], 0, 0, 0);
      acc[0][j][1] = __builtin_amdgcn_mfma_f32_16x16x32_bf16(a0, bd, acc[0][j][1], 0, 0, 0);
      acc[1][j][1] = __builtin_amdgcn_mfma_f32_16x16x32_bf16(a1, bd, acc[1][j][1], 0, 0, 0);
    }
  }

  #pragma unroll
  for(int a=0;a<2;a++){
    #pragma unroll
    for(int r=0;r<4;r++){
      int row = m0 + a*16 + lk*4 + r;
      if(row < N_NODES){
        size_t base = (size_t)row*D_OUT;
        #pragma unroll
        for(int j=0;j<4;j++){
          int col = c0 + j*16 + lr;
          hs2[base + col] = f2bf(acc[a][j][0][r]);
          hd2[base + col] = f2bf(acc[a][j][1][r]);
        }
      }
    }
  }
}

// ---------------- Layer 2 fused: scores + online softmax + aggregate ----------------
__global__ void k_fused2(const unsigned short* __restrict__ hs2, const unsigned short* __restrict__ hd2,
                         const int* __restrict__ es, const int* __restrict__ row_ptr,
                         const int* __restrict__ eidx, const float* __restrict__ attn2,
                         float* __restrict__ h2){
  int node = blockIdx.x*4 + (threadIdx.x >> 6);
  int l = threadIdx.x & 63;
  if(node >= N_NODES) return;
  int rp = row_ptr[node], re = row_ptr[node+1];
  const ushort4* pd = (const ushort4*)(hd2 + (size_t)node*D_OUT);
  const float4*  pa = (const float4*)attn2;
  float4 hd0 = bf4_to_f4(pd[l]), hd1v = bf4_to_f4(pd[64+l]), hd2v = bf4_to_f4(pd[128+l]);
  float4 aw0 = pa[l], aw1 = pa[64+l], aw2 = pa[128+l];
  float m = -INFINITY, den = 0.f;
  float4 ac0 = make_float4(0,0,0,0), ac1 = make_float4(0,0,0,0), ac2 = make_float4(0,0,0,0);
  for(int k=rp; k<re; k++){
    int e = eidx[k]; int s = es[e];
    const ushort4* ps = (const ushort4*)(hs2 + (size_t)s*D_OUT);
    float4 v0 = bf4_to_f4(ps[l]), v1 = bf4_to_f4(ps[64+l]), v2 = bf4_to_f4(ps[128+l]);
    float sc = leaky1(v0.x+hd0.x)*aw0.x + leaky1(v0.y+hd0.y)*aw0.y
             + leaky1(v0.z+hd0.z)*aw0.z + leaky1(v0.w+hd0.w)*aw0.w
             + leaky1(v1.x+hd1v.x)*aw1.x + leaky1(v1.y+hd1v.y)*aw1.y
             + leaky1(v1.z+hd1v.z)*aw1.z + leaky1(v1.w+hd1v.w)*aw1.w
             + leaky1(v2.x+hd2v.x)*aw2.x + leaky1(v2.y+hd2v.y)*aw2.y
             + leaky1(v2.z+hd2v.z)*aw2.z + leaky1(v2.w+hd2v.w)*aw2.w;
    #pragma unroll
    for(int off=1; off<64; off<<=1) sc += __shfl_xor(sc, off, 64);
    float mn = fmaxf(m, sc);
    float r = expf(m - mn);
    float w = expf(sc - mn);
    den = den*r + w;
    ac0.x = ac0.x*r + w*v0.x; ac0.y = ac0.y*r + w*v0.y;
    ac0.z = ac0.z*r + w*v0.z; ac0.w = ac0.w*r + w*v0.w;
    ac1.x = ac1.x*r + w*v1.x; ac1.y = ac1.y*r + w*v1.y;
    ac1.z = ac1.z*r + w*v1.z; ac1.w = ac1.w*r + w*v1.w;
    ac2.x = ac2.x*r + w*v2.x; ac2.y = ac2.y*r + w*v2.y;
    ac2.z = ac2.z*r + w*v2.z; ac2.w = ac2.w*r + w*v2.w;
    m = mn;
  }
  float rd = 1.f/den;
  float4* po = (float4*)(h2 + (size_t)node*D_OUT);
  ac0.x*=rd; ac0.y*=rd; ac0.z*=rd; ac0.w*=rd;
  ac1.x*=rd; ac1.y*=rd; ac1.z*=rd; ac1.w*=rd;
  ac2.x*=rd; ac2.y*=rd; ac2.z*=rd; ac2.w*=rd;
  po[l] = ac0; po[64+l] = ac1; po[128+l] = ac2;
}

// ---------------- Output assembly ----------------
__global__ __launch_bounds__(192) void k_out(const float* __restrict__ h2,
    const int* __restrict__ tok, const int* __restrict__ mins, const int* __restrict__ wkd,
    const int* __restrict__ dayl, const int* __restrict__ grd,
    const float* __restrict__ grid_t, const float* __restrict__ dayt_t,
    const float* __restrict__ week_t, const float* __restrict__ day_t,
    float* __restrict__ out){
  int bs = blockIdx.x;
  int t  = threadIdx.x;
  int s  = bs & (S_LEN-1);
  int tk = tok[bs], mn = mins[bs], wk = wkd[bs], dy = dayl[bs], gr = grd[bs];
  float4 r = ((const float4*)(h2 + (size_t)tk*D_OUT))[t];
  float4 v;
  v = ((const float4*)(week_t + (size_t)wk*D_OUT))[t]; r.x+=v.x; r.y+=v.y; r.z+=v.z; r.w+=v.w;
  v = ((const float4*)(dayt_t + (size_t)mn*D_OUT))[t]; r.x+=v.x; r.y+=v.y; r.z+=v.z; r.w+=v.w;
  v = ((const float4*)(day_t  + (size_t)dy*D_OUT))[t]; r.x+=v.x; r.y+=v.y; r.z+=v.z; r.w+=v.w;
  v = ((const float4*)(grid_t + (size_t)gr*D_OUT))[t]; r.x+=v.x; r.y+=v.y; r.z+=v.z; r.w+=v.w;
  const float K = 0.011992630692677313f;   // ln(10000)/768
  float d0 = expf(-K * (float)(4*t));
  float d1 = expf(-K * (float)(4*t+2));
  float sf = (float)s;
  r.x += sinf(sf*d0); r.y += cosf(sf*d0);
  r.z += sinf(sf*d1); r.w += cosf(sf*d1);
  ((float4*)(out + (size_t)bs*D_OUT))[t] = r;
}

extern "C" void kernel_launch(void* const* d_in, const int* in_sizes, int n_in,
                              void* d_out, int out_size, void* d_ws, size_t ws_size,
                              hipStream_t stream) {
  const int*   trj   = (const int*)  d_in[0];
  const int*   mins  = (const int*)  d_in[1];
  const int*   wkd   = (const int*)  d_in[2];
  const int*   dayl  = (const int*)  d_in[3];
  const int*   grd   = (const int*)  d_in[4];
  const int*   es    = (const int*)  d_in[6];
  const int*   ed    = (const int*)  d_in[7];
  const float* feat  = (const float*)d_in[8];
  const float* Ws1   = (const float*)d_in[9];
  const float* Wd1   = (const float*)d_in[10];
  const float* attn1 = (const float*)d_in[11];
  const float* Ws2   = (const float*)d_in[12];
  const float* Wd2   = (const float*)d_in[13];
  const float* attn2 = (const float*)d_in[14];
  const float* gridt = (const float*)d_in[15];
  const float* daytt = (const float*)d_in[16];
  const float* weekt = (const float*)d_in[17];
  const float* dayt  = (const float*)d_in[18];
  float* out = (float*)d_out;

  char* ws = (char*)d_ws;
  size_t off = 0;
  auto alloc = [&](size_t bytes)->char*{
    char* p = ws + off;
    off += bytes;
    off = (off + 255) & ~(size_t)255;
    return p;
  };
  unsigned short* hs1 = (unsigned short*)alloc((size_t)N_NODES*D_H1*2);
  unsigned short* hd1 = (unsigned short*)alloc((size_t)N_NODES*D_H1*2);
  unsigned short* h1  = (unsigned short*)alloc((size_t)N_NODES*D_H1*2);
  unsigned short* WtS = (unsigned short*)alloc((size_t)D_OUT*D_H1*2);
  unsigned short* WtD = (unsigned short*)alloc((size_t)D_OUT*D_H1*2);
  unsigned short* hs2 = (unsigned short*)alloc((size_t)N_NODES*D_OUT*2);
  unsigned short* hd2 = (unsigned short*)alloc((size_t)N_NODES*D_OUT*2);
  float*          h2  = (float*)         alloc((size_t)N_NODES*D_OUT*4);
  int* deg      = (int*)alloc((size_t)N_NODES*4);
  int* row_ptr  = (int*)alloc((size_t)(N_NODES+1)*4);
  int* cursor   = (int*)alloc((size_t)N_NODES*4);
  int* eidx     = (int*)alloc((size_t)N_EDGES*4);

  // CSR by destination (ws re-poisoned each run -> must zero deg)
  hipMemsetAsync(deg, 0, (size_t)N_NODES*4, stream);
  k_count  <<<(N_EDGES+255)/256, 256, 0, stream>>>(ed, deg);
  k_scan   <<<1, 256, 0, stream>>>(deg, row_ptr, cursor);
  k_scatter<<<(N_EDGES+255)/256, 256, 0, stream>>>(ed, cursor, eidx);

  // Layer 1
  k_gemm1 <<<(N_NODES*D_H1)/256, 256, 0, stream>>>(feat, Ws1, Wd1, hs1, hd1);
  k_fused1<<<(N_NODES+3)/4, 256, 0, stream>>>(hs1, hd1, es, row_ptr, eidx, attn1, h1);

  // Layer 2 (MFMA)
  k_wprep <<<(D_OUT*D_H1+255)/256, 256, 0, stream>>>(Ws2, Wd2, WtS, WtD);
  dim3 g2((N_NODES+63)/64, D_OUT/128);
  k_gemm2m<<<g2, 256, 0, stream>>>(h1, WtS, WtD, hs2, hd2);
  k_fused2<<<(N_NODES+3)/4, 256, 0, stream>>>(hs2, hd2, es, row_ptr, eidx, attn2, h2);

  // Output
  k_out<<<B_SZ*S_LEN, 192, 0, stream>>>(h2, trj, mins, wkd, dayl, grd,
                                        gridt, daytt, weekt, dayt, out);
}

// Round 10
// 360.461 us; speedup vs baseline: 2.0213x; 1.0402x over previous
//
#include <hip/hip_runtime.h>
#include <hip/hip_bf16.h>

#define N_NODES 20000
#define N_EDGES 180000
#define D_OUT   768
#define D_H1    128
#define B_SZ    16
#define S_LEN   512
#define NEG_SLOPE_C 0.2f

typedef __attribute__((ext_vector_type(8))) short bf16x8;   // 8 bf16 = 4 VGPRs
typedef __attribute__((ext_vector_type(4))) float f32x4;    // MFMA acc

__device__ __forceinline__ float leaky1(float x){ return x >= 0.0f ? x : NEG_SLOPE_C * x; }
__device__ __forceinline__ unsigned short f2bf(float x){
  union { __hip_bfloat16 h; unsigned short u; } v; v.h = __float2bfloat16(x); return v.u;
}
__device__ __forceinline__ float bf2f(unsigned short u){
  return __uint_as_float(((unsigned)u) << 16);
}
__device__ __forceinline__ float4 bf4_to_f4(ushort4 u){
  return make_float4(bf2f(u.x), bf2f(u.y), bf2f(u.z), bf2f(u.w));
}

// ---------------- CSR build (by destination) ----------------
__global__ void k_count(const int* __restrict__ ed, int* __restrict__ deg){
  int e = blockIdx.x*256 + threadIdx.x;
  if(e < N_EDGES) atomicAdd(&deg[ed[e]], 1);
}

__global__ void k_scan(const int* __restrict__ deg, int* __restrict__ row_ptr, int* __restrict__ cursor){
  __shared__ int part[256];
  int t = threadIdx.x;
  const int CH = (N_NODES + 255) / 256;
  int base = t * CH;
  int s = 0;
  for(int i=0;i<CH;i++){ int n = base+i; if(n < N_NODES) s += deg[n]; }
  part[t] = s;
  __syncthreads();
  for(int off=1; off<256; off<<=1){
    int v = (t >= off) ? part[t-off] : 0;
    __syncthreads();
    part[t] += v;
    __syncthreads();
  }
  int run = (t==0) ? 0 : part[t-1];
  for(int i=0;i<CH;i++){
    int n = base+i;
    if(n < N_NODES){ row_ptr[n] = run; cursor[n] = run; run += deg[n]; }
  }
  if(t == 255) row_ptr[N_NODES] = run;
}

__global__ void k_scatter(const int* __restrict__ ed, int* __restrict__ cursor, int* __restrict__ eidx){
  int e = blockIdx.x*256 + threadIdx.x;
  if(e < N_EDGES){
    int pos = atomicAdd(&cursor[ed[e]], 1);
    eidx[pos] = e;
  }
}

// ---------------- Layer 1: node transforms (K=4), bf16 outputs ----------------
__global__ void k_gemm1(const float* __restrict__ feat, const float* __restrict__ Ws,
                        const float* __restrict__ Wd,
                        unsigned short* __restrict__ hs1, unsigned short* __restrict__ hd1){
  int idx = blockIdx.x*256 + threadIdx.x;
  if(idx >= N_NODES*D_H1) return;
  int n = idx >> 7, hf = idx & 127;
  float f0 = feat[n*4+0], f1 = feat[n*4+1], f2 = feat[n*4+2], f3 = feat[n*4+3];
  hs1[idx] = f2bf(f0*Ws[hf] + f1*Ws[128+hf] + f2*Ws[256+hf] + f3*Ws[384+hf]);
  hd1[idx] = f2bf(f0*Wd[hf] + f1*Wd[128+hf] + f2*Wd[256+hf] + f3*Wd[384+hf]);
}

// ---------------- Layer 1 fused (unroll-2): scores + online softmax + aggregate + ELU ----------------
// wave per node; per-16-lane-group head softmax; two edges in flight per iter.
__global__ void k_fused1(const unsigned short* __restrict__ hs1, const unsigned short* __restrict__ hd1,
                         const int* __restrict__ es, const int* __restrict__ row_ptr,
                         const int* __restrict__ eidx, const float* __restrict__ attn1,
                         unsigned short* __restrict__ h1){
  int node = blockIdx.x*4 + (threadIdx.x >> 6);
  int l = threadIdx.x & 63;
  if(node >= N_NODES) return;
  int rp = row_ptr[node], re = row_ptr[node+1];
  float hda = bf2f(hd1[(size_t)node*D_H1 + l]);
  float hdb = bf2f(hd1[(size_t)node*D_H1 + 64 + l]);
  float awa = attn1[l], awb = attn1[64 + l];
  float m0 = -INFINITY, m1 = -INFINITY;
  float d0 = 0.f, d1 = 0.f, a0 = 0.f, a1 = 0.f;
  int k = rp;
  for(; k+1 < re; k += 2){
    int e0 = eidx[k], e1 = eidx[k+1];
    int s0 = es[e0],  s1 = es[e1];
    // two independent gathers in flight
    float xa0 = bf2f(hs1[(size_t)s0*D_H1 + l]);
    float xb0 = bf2f(hs1[(size_t)s0*D_H1 + 64 + l]);
    float xa1 = bf2f(hs1[(size_t)s1*D_H1 + l]);
    float xb1 = bf2f(hs1[(size_t)s1*D_H1 + 64 + l]);
    float ta0 = leaky1(xa0 + hda) * awa;
    float tb0 = leaky1(xb0 + hdb) * awb;
    float ta1 = leaky1(xa1 + hda) * awa;
    float tb1 = leaky1(xb1 + hdb) * awb;
    #pragma unroll
    for(int off=1; off<16; off<<=1){
      ta0 += __shfl_xor(ta0, off, 64);
      tb0 += __shfl_xor(tb0, off, 64);
      ta1 += __shfl_xor(ta1, off, 64);
      tb1 += __shfl_xor(tb1, off, 64);
    }
    // one merged online update per pair
    float mn0 = fmaxf(m0, fmaxf(ta0, ta1));
    float mn1 = fmaxf(m1, fmaxf(tb0, tb1));
    float r0 = expf(m0 - mn0), r1 = expf(m1 - mn1);   // first iter: expf(-inf)=0
    float wa0 = expf(ta0 - mn0), wa1 = expf(ta1 - mn0);
    float wb0 = expf(tb0 - mn1), wb1 = expf(tb1 - mn1);
    d0 = d0*r0 + wa0 + wa1;
    d1 = d1*r1 + wb0 + wb1;
    a0 = a0*r0 + wa0*xa0 + wa1*xa1;
    a1 = a1*r1 + wb0*xb0 + wb1*xb1;
    m0 = mn0; m1 = mn1;
  }
  if(k < re){  // epilogue edge
    int e = eidx[k]; int s = es[e];
    float xa = bf2f(hs1[(size_t)s*D_H1 + l]);
    float xb = bf2f(hs1[(size_t)s*D_H1 + 64 + l]);
    float t0 = leaky1(xa + hda) * awa;
    float t1 = leaky1(xb + hdb) * awb;
    #pragma unroll
    for(int off=1; off<16; off<<=1){
      t0 += __shfl_xor(t0, off, 64);
      t1 += __shfl_xor(t1, off, 64);
    }
    float mn0 = fmaxf(m0, t0), mn1 = fmaxf(m1, t1);
    float r0 = expf(m0 - mn0), r1 = expf(m1 - mn1);
    float w0 = expf(t0 - mn0), w1 = expf(t1 - mn1);
    d0 = d0*r0 + w0;      d1 = d1*r1 + w1;
    a0 = a0*r0 + w0*xa;   a1 = a1*r1 + w1*xb;
    m0 = mn0; m1 = mn1;
  }
  float v0 = a0 / d0, v1 = a1 / d1;
  v0 = v0 > 0.f ? v0 : expm1f(v0);
  v1 = v1 > 0.f ? v1 : expm1f(v1);
  h1[(size_t)node*D_H1 + l]      = f2bf(v0);
  h1[(size_t)node*D_H1 + 64 + l] = f2bf(v1);
}

// ---------------- W2 prep: fp32 [k][768] -> bf16 transposed [col][k] ----------------
__global__ void k_wprep(const float* __restrict__ Ws, const float* __restrict__ Wd,
                        unsigned short* __restrict__ WtS, unsigned short* __restrict__ WtD){
  int i = blockIdx.x*256 + threadIdx.x;   // over 768*128
  if(i >= D_OUT*D_H1) return;
  int c = i >> 7, k = i & 127;
  WtS[i] = f2bf(Ws[(size_t)k*D_OUT + c]);
  WtD[i] = f2bf(Wd[(size_t)k*D_OUT + c]);
}

// ---------------- Layer 2: MFMA bf16 GEMM (20000x128)@(128x768), both mats ----------------
__global__ __launch_bounds__(256) void k_gemm2m(const unsigned short* __restrict__ h1b,
                        const unsigned short* __restrict__ WtS, const unsigned short* __restrict__ WtD,
                        unsigned short* __restrict__ hs2, unsigned short* __restrict__ hd2){
  int wave = threadIdx.x >> 6, lane = threadIdx.x & 63;
  int wr = wave >> 1, wc = wave & 1;
  int m0 = blockIdx.x*64 + wr*32;
  int c0 = blockIdx.y*128 + wc*64;
  int lr = lane & 15, lk = lane >> 4;

  f32x4 acc[2][4][2];
  #pragma unroll
  for(int a=0;a<2;a++)
    #pragma unroll
    for(int j=0;j<4;j++)
      #pragma unroll
      for(int mmat=0;mmat<2;mmat++)
        acc[a][j][mmat] = (f32x4){0.f,0.f,0.f,0.f};

  int ra0 = m0 + lr;      if(ra0 > N_NODES-1) ra0 = N_NODES-1;
  int ra1 = m0 + 16 + lr; if(ra1 > N_NODES-1) ra1 = N_NODES-1;
  const unsigned short* pa0 = h1b + (size_t)ra0*D_H1 + lk*8;
  const unsigned short* pa1 = h1b + (size_t)ra1*D_H1 + lk*8;

  #pragma unroll
  for(int t=0;t<4;t++){              // K = 4 x 32
    bf16x8 a0 = *(const bf16x8*)(pa0 + t*32);
    bf16x8 a1 = *(const bf16x8*)(pa1 + t*32);
    #pragma unroll
    for(int j=0;j<4;j++){
      size_t bo = (size_t)(c0 + j*16 + lr)*D_H1 + t*32 + lk*8;
      bf16x8 bs = *(const bf16x8*)(WtS + bo);
      bf16x8 bd = *(const bf16x8*)(WtD + bo);
      acc[0][j][0] = __builtin_amdgcn_mfma_f32_16x16x32_bf16(a0, bs, acc[0][j][0], 0, 0, 0);
      acc[1][j][0] = __builtin_amdgcn_mfma_f32_16x16x32_bf16(a1, bs, acc[1][j][0], 0, 0, 0);
      acc[0][j][1] = __builtin_amdgcn_mfma_f32_16x16x32_bf16(a0, bd, acc[0][j][1], 0, 0, 0);
      acc[1][j][1] = __builtin_amdgcn_mfma_f32_16x16x32_bf16(a1, bd, acc[1][j][1], 0, 0, 0);
    }
  }

  #pragma unroll
  for(int a=0;a<2;a++){
    #pragma unroll
    for(int r=0;r<4;r++){
      int row = m0 + a*16 + lk*4 + r;
      if(row < N_NODES){
        size_t base = (size_t)row*D_OUT;
        #pragma unroll
        for(int j=0;j<4;j++){
          int col = c0 + j*16 + lr;
          hs2[base + col] = f2bf(acc[a][j][0][r]);
          hd2[base + col] = f2bf(acc[a][j][1][r]);
        }
      }
    }
  }
}

// ---------------- Layer 2 fused (unroll-2): scores + online softmax + aggregate ----------------
// wave per node; hd2[node] in regs; two hs2-row gathers in flight; wave-uniform rescale branch.
__global__ void k_fused2(const unsigned short* __restrict__ hs2, const unsigned short* __restrict__ hd2,
                         const int* __restrict__ es, const int* __restrict__ row_ptr,
                         const int* __restrict__ eidx, const float* __restrict__ attn2,
                         float* __restrict__ h2){
  int node = blockIdx.x*4 + (threadIdx.x >> 6);
  int l = threadIdx.x & 63;
  if(node >= N_NODES) return;
  int rp = row_ptr[node], re = row_ptr[node+1];
  const ushort4* pd = (const ushort4*)(hd2 + (size_t)node*D_OUT);
  const float4*  pa = (const float4*)attn2;
  float4 hd0 = bf4_to_f4(pd[l]), hd1v = bf4_to_f4(pd[64+l]), hd2v = bf4_to_f4(pd[128+l]);
  float4 aw0 = pa[l], aw1 = pa[64+l], aw2 = pa[128+l];
  float m = -INFINITY, den = 0.f;
  float4 ac0 = make_float4(0,0,0,0), ac1 = make_float4(0,0,0,0), ac2 = make_float4(0,0,0,0);
  int k = rp;
  for(; k+1 < re; k += 2){
    int e0 = eidx[k], e1 = eidx[k+1];
    int s0 = es[e0],  s1 = es[e1];
    const ushort4* psA = (const ushort4*)(hs2 + (size_t)s0*D_OUT);
    const ushort4* psB = (const ushort4*)(hs2 + (size_t)s1*D_OUT);
    float4 u0 = bf4_to_f4(psA[l]), u1 = bf4_to_f4(psA[64+l]), u2 = bf4_to_f4(psA[128+l]);
    float4 v0 = bf4_to_f4(psB[l]), v1 = bf4_to_f4(psB[64+l]), v2 = bf4_to_f4(psB[128+l]);
    float scA = leaky1(u0.x+hd0.x)*aw0.x + leaky1(u0.y+hd0.y)*aw0.y
              + leaky1(u0.z+hd0.z)*aw0.z + leaky1(u0.w+hd0.w)*aw0.w
              + leaky1(u1.x+hd1v.x)*aw1.x + leaky1(u1.y+hd1v.y)*aw1.y
              + leaky1(u1.z+hd1v.z)*aw1.z + leaky1(u1.w+hd1v.w)*aw1.w
              + leaky1(u2.x+hd2v.x)*aw2.x + leaky1(u2.y+hd2v.y)*aw2.y
              + leaky1(u2.z+hd2v.z)*aw2.z + leaky1(u2.w+hd2v.w)*aw2.w;
    float scB = leaky1(v0.x+hd0.x)*aw0.x + leaky1(v0.y+hd0.y)*aw0.y
              + leaky1(v0.z+hd0.z)*aw0.z + leaky1(v0.w+hd0.w)*aw0.w
              + leaky1(v1.x+hd1v.x)*aw1.x + leaky1(v1.y+hd1v.y)*aw1.y
              + leaky1(v1.z+hd1v.z)*aw1.z + leaky1(v1.w+hd1v.w)*aw1.w
              + leaky1(v2.x+hd2v.x)*aw2.x + leaky1(v2.y+hd2v.y)*aw2.y
              + leaky1(v2.z+hd2v.z)*aw2.z + leaky1(v2.w+hd2v.w)*aw2.w;
    #pragma unroll
    for(int off=1; off<64; off<<=1){
      scA += __shfl_xor(scA, off, 64);
      scB += __shfl_xor(scB, off, 64);
    }
    float mn = fmaxf(m, fmaxf(scA, scB));
    if(mn > m){                       // wave-uniform branch (sc uniform after reduce)
      float r = expf(m - mn);         // first iter: expf(-inf)=0
      den *= r;
      ac0.x*=r; ac0.y*=r; ac0.z*=r; ac0.w*=r;
      ac1.x*=r; ac1.y*=r; ac1.z*=r; ac1.w*=r;
      ac2.x*=r; ac2.y*=r; ac2.z*=r; ac2.w*=r;
      m = mn;
    }
    float wA = expf(scA - m), wB = expf(scB - m);
    den += wA + wB;
    ac0.x += wA*u0.x + wB*v0.x; ac0.y += wA*u0.y + wB*v0.y;
    ac0.z += wA*u0.z + wB*v0.z; ac0.w += wA*u0.w + wB*v0.w;
    ac1.x += wA*u1.x + wB*v1.x; ac1.y += wA*u1.y + wB*v1.y;
    ac1.z += wA*u1.z + wB*v1.z; ac1.w += wA*u1.w + wB*v1.w;
    ac2.x += wA*u2.x + wB*v2.x; ac2.y += wA*u2.y + wB*v2.y;
    ac2.z += wA*u2.z + wB*v2.z; ac2.w += wA*u2.w + wB*v2.w;
  }
  if(k < re){  // epilogue edge
    int e = eidx[k]; int s = es[e];
    const ushort4* ps = (const ushort4*)(hs2 + (size_t)s*D_OUT);
    float4 u0 = bf4_to_f4(ps[l]), u1 = bf4_to_f4(ps[64+l]), u2 = bf4_to_f4(ps[128+l]);
    float sc = leaky1(u0.x+hd0.x)*aw0.x + leaky1(u0.y+hd0.y)*aw0.y
             + leaky1(u0.z+hd0.z)*aw0.z + leaky1(u0.w+hd0.w)*aw0.w
             + leaky1(u1.x+hd1v.x)*aw1.x + leaky1(u1.y+hd1v.y)*aw1.y
             + leaky1(u1.z+hd1v.z)*aw1.z + leaky1(u1.w+hd1v.w)*aw1.w
             + leaky1(u2.x+hd2v.x)*aw2.x + leaky1(u2.y+hd2v.y)*aw2.y
             + leaky1(u2.z+hd2v.z)*aw2.z + leaky1(u2.w+hd2v.w)*aw2.w;
    #pragma unroll
    for(int off=1; off<64; off<<=1) sc += __shfl_xor(sc, off, 64);
    float mn = fmaxf(m, sc);
    if(mn > m){
      float r = expf(m - mn);
      den *= r;
      ac0.x*=r; ac0.y*=r; ac0.z*=r; ac0.w*=r;
      ac1.x*=r; ac1.y*=r; ac1.z*=r; ac1.w*=r;
      ac2.x*=r; ac2.y*=r; ac2.z*=r; ac2.w*=r;
      m = mn;
    }
    float w = expf(sc - m);
    den += w;
    ac0.x += w*u0.x; ac0.y += w*u0.y; ac0.z += w*u0.z; ac0.w += w*u0.w;
    ac1.x += w*u1.x; ac1.y += w*u1.y; ac1.z += w*u1.z; ac1.w += w*u1.w;
    ac2.x += w*u2.x; ac2.y += w*u2.y; ac2.z += w*u2.z; ac2.w += w*u2.w;
  }
  float rd = 1.f/den;
  float4* po = (float4*)(h2 + (size_t)node*D_OUT);
  ac0.x*=rd; ac0.y*=rd; ac0.z*=rd; ac0.w*=rd;
  ac1.x*=rd; ac1.y*=rd; ac1.z*=rd; ac1.w*=rd;
  ac2.x*=rd; ac2.y*=rd; ac2.z*=rd; ac2.w*=rd;
  po[l] = ac0; po[64+l] = ac1; po[128+l] = ac2;
}

// ---------------- Output assembly ----------------
__global__ __launch_bounds__(192) void k_out(const float* __restrict__ h2,
    const int* __restrict__ tok, const int* __restrict__ mins, const int* __restrict__ wkd,
    const int* __restrict__ dayl, const int* __restrict__ grd,
    const float* __restrict__ grid_t, const float* __restrict__ dayt_t,
    const float* __restrict__ week_t, const float* __restrict__ day_t,
    float* __restrict__ out){
  int bs = blockIdx.x;
  int t  = threadIdx.x;
  int s  = bs & (S_LEN-1);
  int tk = tok[bs], mn = mins[bs], wk = wkd[bs], dy = dayl[bs], gr = grd[bs];
  float4 r = ((const float4*)(h2 + (size_t)tk*D_OUT))[t];
  float4 v;
  v = ((const float4*)(week_t + (size_t)wk*D_OUT))[t]; r.x+=v.x; r.y+=v.y; r.z+=v.z; r.w+=v.w;
  v = ((const float4*)(dayt_t + (size_t)mn*D_OUT))[t]; r.x+=v.x; r.y+=v.y; r.z+=v.z; r.w+=v.w;
  v = ((const float4*)(day_t  + (size_t)dy*D_OUT))[t]; r.x+=v.x; r.y+=v.y; r.z+=v.z; r.w+=v.w;
  v = ((const float4*)(grid_t + (size_t)gr*D_OUT))[t]; r.x+=v.x; r.y+=v.y; r.z+=v.z; r.w+=v.w;
  const float K = 0.011992630692677313f;   // ln(10000)/768
  float d0 = expf(-K * (float)(4*t));
  float d1 = expf(-K * (float)(4*t+2));
  float sf = (float)s;
  r.x += sinf(sf*d0); r.y += cosf(sf*d0);
  r.z += sinf(sf*d1); r.w += cosf(sf*d1);
  ((float4*)(out + (size_t)bs*D_OUT))[t] = r;
}

extern "C" void kernel_launch(void* const* d_in, const int* in_sizes, int n_in,
                              void* d_out, int out_size, void* d_ws, size_t ws_size,
                              hipStream_t stream) {
  const int*   trj   = (const int*)  d_in[0];
  const int*   mins  = (const int*)  d_in[1];
  const int*   wkd   = (const int*)  d_in[2];
  const int*   dayl  = (const int*)  d_in[3];
  const int*   grd   = (const int*)  d_in[4];
  const int*   es    = (const int*)  d_in[6];
  const int*   ed    = (const int*)  d_in[7];
  const float* feat  = (const float*)d_in[8];
  const float* Ws1   = (const float*)d_in[9];
  const float* Wd1   = (const float*)d_in[10];
  const float* attn1 = (const float*)d_in[11];
  const float* Ws2   = (const float*)d_in[12];
  const float* Wd2   = (const float*)d_in[13];
  const float* attn2 = (const float*)d_in[14];
  const float* gridt = (const float*)d_in[15];
  const float* daytt = (const float*)d_in[16];
  const float* weekt = (const float*)d_in[17];
  const float* dayt  = (const float*)d_in[18];
  float* out = (float*)d_out;

  char* ws = (char*)d_ws;
  size_t off = 0;
  auto alloc = [&](size_t bytes)->char*{
    char* p = ws + off;
    off += bytes;
    off = (off + 255) & ~(size_t)255;
    return p;
  };
  unsigned short* hs1 = (unsigned short*)alloc((size_t)N_NODES*D_H1*2);
  unsigned short* hd1 = (unsigned short*)alloc((size_t)N_NODES*D_H1*2);
  unsigned short* h1  = (unsigned short*)alloc((size_t)N_NODES*D_H1*2);
  unsigned short* WtS = (unsigned short*)alloc((size_t)D_OUT*D_H1*2);
  unsigned short* WtD = (unsigned short*)alloc((size_t)D_OUT*D_H1*2);
  unsigned short* hs2 = (unsigned short*)alloc((size_t)N_NODES*D_OUT*2);
  unsigned short* hd2 = (unsigned short*)alloc((size_t)N_NODES*D_OUT*2);
  float*          h2  = (float*)         alloc((size_t)N_NODES*D_OUT*4);
  int* deg      = (int*)alloc((size_t)N_NODES*4);
  int* row_ptr  = (int*)alloc((size_t)(N_NODES+1)*4);
  int* cursor   = (int*)alloc((size_t)N_NODES*4);
  int* eidx     = (int*)alloc((size_t)N_EDGES*4);

  // CSR by destination (ws re-poisoned each run -> must zero deg)
  hipMemsetAsync(deg, 0, (size_t)N_NODES*4, stream);
  k_count  <<<(N_EDGES+255)/256, 256, 0, stream>>>(ed, deg);
  k_scan   <<<1, 256, 0, stream>>>(deg, row_ptr, cursor);
  k_scatter<<<(N_EDGES+255)/256, 256, 0, stream>>>(ed, cursor, eidx);

  // Layer 1
  k_gemm1 <<<(N_NODES*D_H1)/256, 256, 0, stream>>>(feat, Ws1, Wd1, hs1, hd1);
  k_fused1<<<(N_NODES+3)/4, 256, 0, stream>>>(hs1, hd1, es, row_ptr, eidx, attn1, h1);

  // Layer 2 (MFMA)
  k_wprep <<<(D_OUT*D_H1+255)/256, 256, 0, stream>>>(Ws2, Wd2, WtS, WtD);
  dim3 g2((N_NODES+63)/64, D_OUT/128);
  k_gemm2m<<<g2, 256, 0, stream>>>(h1, WtS, WtD, hs2, hd2);
  k_fused2<<<(N_NODES+3)/4, 256, 0, stream>>>(hs2, hd2, es, row_ptr, eidx, attn2, h2);

  // Output
  k_out<<<B_SZ*S_LEN, 192, 0, stream>>>(h2, trj, mins, wkd, dayl, grd,
                                        gridt, daytt, weekt, dayt, out);
}